// Round 10
// baseline (102.797 us; speedup 1.0000x reference)
//
#include <hip/hip_runtime.h>

#define BLK 256
#define QPT 16       // query points per thread (packed f32x2, named scalars)
#define SLICES 32    // target slices per direction
#define TT 256       // targets per slice tile (= 8192 / SLICES)
#define CP (TT / 2)  // column pairs per tile (128)

typedef float f32x2 __attribute__((ext_vector_type(2)));

#define Q_ITER(F) F(0) F(1) F(2) F(3) F(4) F(5) F(6) F(7) \
                  F(8) F(9) F(10) F(11) F(12) F(13) F(14) F(15)

__global__ __launch_bounds__(256) void init_mins(unsigned int* mins, int n) {
    int i = blockIdx.x * 256 + threadIdx.x;
    if (i < n) mins[i] = 0x7f800000u;  // +inf
}

// dir 0: queries = pred (pc_p), targets = gt  -> P region
// dir 1: queries = gt  (pc_gt), targets = pred -> G region
// waves_per_eu(4,4): min=max=4 waves/EU. Staying <=64 VGPR buys no occupancy
// (max is capped), so the allocator uses the 128-VGPR budget instead of
// spilling (r3/r4/r9 failure mode: allocator chased 8 waves/EU via scratch).
template <bool USE_ATOMIC>
__global__ __launch_bounds__(BLK)
__attribute__((amdgpu_waves_per_eu(4, 4)))
void chamfer_min(
    const float* __restrict__ gt, const float* __restrict__ pp,
    unsigned int* __restrict__ minP, unsigned int* __restrict__ minG,
    float* __restrict__ dP, float* __restrict__ dG,
    int M, int N)
{
    const int dir = (blockIdx.z >= SLICES) ? 1 : 0;
    const int s   = blockIdx.z - dir * SLICES;
    const float* __restrict__ Q = dir ? gt : pp;
    const float* __restrict__ T = dir ? pp : gt;
    const int NQ = dir ? N : M;
    const int NT = dir ? M : N;
    const int b  = blockIdx.y;

    // Column-pair halves in two 16B-stride arrays, MIRRORED to 256 entries so
    // lane-staggered reads sH[p + lane] (p<128, lane<64) need no wrap.
    //   sH0[p] = {-2zA,-2zB,-2yA,-2yB}   sH1[p] = {-2xA,-2xB, wA, wB}
    __shared__ float4 sH0[2 * CP];
    __shared__ float4 sH1[2 * CP];
    {
        const int t = threadIdx.x;          // 0..255
        const int pIdx = t & (CP - 1);      // pair index
        const int mir  = t >> 7;            // 0 = original, 1 = mirror copy
        const float2* tb2 = (const float2*)(T + ((size_t)b * NT + (size_t)s * TT) * 3);
        float2 u0 = tb2[3 * pIdx], u1 = tb2[3 * pIdx + 1], u2 = tb2[3 * pIdx + 2];
        float xA = u0.x, yA = u0.y, zA = u1.x;
        float xB = u1.y, yB = u2.x, zB = u2.y;
        int w = mir * CP + pIdx;
        sH0[w] = make_float4(-2.f * zA, -2.f * zB, -2.f * yA, -2.f * yB);
        sH1[w] = make_float4(-2.f * xA, -2.f * xB,
                             xA * xA + yA * yA + zA * zA,
                             xB * xB + yB * yB + zB * zB);
    }
    __syncthreads();

    const int q0 = blockIdx.x * (BLK * QPT) + threadIdx.x * QPT;
    if (q0 >= NQ) return;

    // 16 query points = 48 floats = 12 aligned float4 loads -> named scalars
    const float4* qv = (const float4*)(Q + ((size_t)b * NQ + q0) * 3);
    float4 f0 = qv[0], f1 = qv[1], f2 = qv[2],  f3 = qv[3],  f4 = qv[4],  f5 = qv[5];
    float4 f6 = qv[6], f7 = qv[7], f8 = qv[8],  f9 = qv[9],  fa = qv[10], fb = qv[11];

#define DECLQ(i) float qx##i, qy##i, qz##i, bb##i = 3.0e38f;
    Q_ITER(DECLQ)
#undef DECLQ
    qx0  = f0.x; qy0  = f0.y; qz0  = f0.z;
    qx1  = f0.w; qy1  = f1.x; qz1  = f1.y;
    qx2  = f1.z; qy2  = f1.w; qz2  = f2.x;
    qx3  = f2.y; qy3  = f2.z; qz3  = f2.w;
    qx4  = f3.x; qy4  = f3.y; qz4  = f3.z;
    qx5  = f3.w; qy5  = f4.x; qz5  = f4.y;
    qx6  = f4.z; qy6  = f4.w; qz6  = f5.x;
    qx7  = f5.y; qy7  = f5.z; qz7  = f5.w;
    qx8  = f6.x; qy8  = f6.y; qz8  = f6.z;
    qx9  = f6.w; qy9  = f7.x; qz9  = f7.y;
    qx10 = f7.z; qy10 = f7.w; qz10 = f8.x;
    qx11 = f8.y; qy11 = f8.z; qz11 = f8.w;
    qx12 = f9.x; qy12 = f9.y; qz12 = f9.z;
    qx13 = f9.w; qy13 = fa.x; qz13 = fa.y;
    qx14 = fa.z; qy14 = fa.w; qz14 = fb.x;
    qx15 = fb.y; qy15 = fb.z; qz15 = fb.w;

    // splat to packed halves; backend folds {q,q} into VOP3P op_sel
#define DUPQ(i) f32x2 px##i = {qx##i, qx##i}, py##i = {qy##i, qy##i}, pz##i = {qz##i, qz##i};
    Q_ITER(DUPQ)
#undef DUPQ

    // Lane-staggered walk: lane reads pair (p + lane); min is order-independent.
    const int lane = threadIdx.x & 63;
    for (int p = 0; p < CP; ++p) {
        float4 h0 = sH0[p + lane];
        float4 h1 = sH1[p + lane];
        f32x2 Sz = {h0.x, h0.y};
        f32x2 Sy = {h0.z, h0.w};
        f32x2 Sx = {h1.x, h1.y};
        f32x2 Sw = {h1.z, h1.w};
#define STEP(i) { \
        f32x2 AB = __builtin_elementwise_fma(pz##i, Sz, Sw); \
        AB = __builtin_elementwise_fma(py##i, Sy, AB); \
        AB = __builtin_elementwise_fma(px##i, Sx, AB); \
        bb##i = fminf(fminf(bb##i, AB.x), AB.y); }
        Q_ITER(STEP)
#undef STEP
    }

    unsigned int* mp = (dir ? minG : minP) + (size_t)b * NQ + q0;
    float* op = (dir ? dG : dP) + (size_t)s * ((size_t)gridDim.y * NQ)
                                + (size_t)b * NQ + q0;
#define FIN(i) { \
        float aq = __builtin_fmaf(qx##i, qx##i, \
                   __builtin_fmaf(qy##i, qy##i, qz##i * qz##i)); \
        float d = fmaxf(bb##i + aq, 0.f); \
        if (USE_ATOMIC) atomicMin(&mp[i], __float_as_uint(d)); \
        else op[i] = d; }
    Q_ITER(FIN)
#undef FIN
}

__device__ double block_reduce_d(double v) {
    __shared__ double red[4];
    for (int o = 32; o > 0; o >>= 1) v += __shfl_down(v, o);
    int lane = threadIdx.x & 63, w = threadIdx.x >> 6;
    if (lane == 0) red[w] = v;
    __syncthreads();
    if (threadIdx.x == 0) v = red[0] + red[1] + red[2] + red[3];
    return v;
}

// fold SLICES per-slice mins + weighted sum
__global__ __launch_bounds__(256) void reduce1_slices(
    const float* __restrict__ dP, const float* __restrict__ dG,
    double* __restrict__ partials, int EM, int EN, double wP, double wG) {
    const int E = EM + EN;
    double acc = 0.0;
    for (int i = blockIdx.x * 256 + threadIdx.x; i < E; i += 256 * 256) {
        const float* base; int stride; double w;
        if (i < EM) { base = dP + i;        stride = EM; w = wP; }
        else        { base = dG + (i - EM); stride = EN; w = wG; }
        float m = base[0];
#pragma unroll
        for (int s = 1; s < SLICES; ++s) m = fminf(m, base[(size_t)s * stride]);
        acc += (double)m * w;
    }
    double s = block_reduce_d(acc);
    if (threadIdx.x == 0) partials[blockIdx.x] = s;
}

__global__ __launch_bounds__(256) void reduce1_atomic(
    const unsigned int* __restrict__ mins, double* __restrict__ partials,
    int EM, int E, double wP, double wG) {
    double acc = 0.0;
    for (int i = blockIdx.x * 256 + threadIdx.x; i < E; i += 256 * 256)
        acc += (double)__uint_as_float(mins[i]) * (i < EM ? wP : wG);
    double s = block_reduce_d(acc);
    if (threadIdx.x == 0) partials[blockIdx.x] = s;
}

__global__ __launch_bounds__(256) void reduce2(const double* __restrict__ partials,
                                               float* __restrict__ out) {
    double s = block_reduce_d(partials[threadIdx.x]);
    if (threadIdx.x == 0) out[0] = (float)s;
}

extern "C" void kernel_launch(void* const* d_in, const int* in_sizes, int n_in,
                              void* d_out, int out_size, void* d_ws, size_t ws_size,
                              hipStream_t stream) {
    const float* gt = (const float*)d_in[0];  // pc_gt (B,N,3)
    const float* pp = (const float*)d_in[1];  // pc_p  (B,M,3)
    const int B = 8;
    const int N = in_sizes[0] / (B * 3);
    const int M = in_sizes[1] / (B * 3);
    const int EM = B * M, EN = B * N, E = EM + EN;
    float* out = (float*)d_out;

    const int NQmax = (M > N) ? M : N;
    dim3 grid((NQmax + BLK * QPT - 1) / (BLK * QPT), B, 2 * SLICES);

    const size_t needNA = (size_t)SLICES * E * 4 + 256 * 8;
    if (ws_size >= needNA) {
        // no-atomic path: per-slice buffers + fused slice-min reduction
        float* dP = (float*)d_ws;                       // SLICES x EM
        float* dG = dP + (size_t)SLICES * EM;           // SLICES x EN
        double* partials = (double*)((char*)d_ws + (size_t)SLICES * E * 4);
        chamfer_min<false><<<grid, BLK, 0, stream>>>(gt, pp, nullptr, nullptr,
                                                     dP, dG, M, N);
        reduce1_slices<<<256, 256, 0, stream>>>(dP, dG, partials, EM, EN,
                                                1.0 / (double)EM, 1.0 / (double)EN);
        reduce2<<<1, 256, 0, stream>>>(partials, out);
    } else {
        // fallback: atomic-min path
        unsigned int* mins = (unsigned int*)d_ws;
        double* partials = (double*)((char*)d_ws + (size_t)E * 4);
        init_mins<<<(E + 255) / 256, 256, 0, stream>>>(mins, E);
        chamfer_min<true><<<grid, BLK, 0, stream>>>(gt, pp, mins, mins + EM,
                                                    nullptr, nullptr, M, N);
        reduce1_atomic<<<256, 256, 0, stream>>>(mins, partials, EM, E,
                                                1.0 / (double)EM, 1.0 / (double)EN);
        reduce2<<<1, 256, 0, stream>>>(partials, out);
    }
}

// Round 11
// 101.856 us; speedup vs baseline: 1.0092x; 1.0092x over previous
//
#include <hip/hip_runtime.h>

#define BLK 256
#define QPT 8        // query points per thread (proven no-spill regime)
#define SLICES 16    // target slices per direction
#define TT 512       // targets per slice tile (= 8192 / SLICES)
#define PAIRS (TT / 2)   // 256 column pairs per slice
#define LP 64            // pairs staged in LDS (quarter); 192 read via global/SMEM

typedef float f32x2 __attribute__((ext_vector_type(2)));

#define Q_ITER(F) F(0) F(1) F(2) F(3) F(4) F(5) F(6) F(7)

__global__ __launch_bounds__(256) void init_mins(unsigned int* mins, int n) {
    int i = blockIdx.x * 256 + threadIdx.x;
    if (i < n) mins[i] = 0x7f800000u;  // +inf
}

// Precompute pair-halves for ALL targets once:
//   h0 = {-2zA,-2zB,-2yA,-2yB}   h1 = {-2xA,-2xB, wA, wB}
// Layout: [dir0: b=0..7 x halfN pairs][dir1: b=0..7 x halfM pairs], 32B/pair.
__global__ __launch_bounds__(256) void prep_pairs(
    const float* __restrict__ gt, const float* __restrict__ pp,
    float4* __restrict__ HP, int M, int N)
{
    const int tid = blockIdx.x * 256 + threadIdx.x;
    const int halfN = N >> 1, halfM = M >> 1;
    const int nP0 = 8 * halfN;
    if (tid >= nP0 + 8 * halfM) return;
    const float* T; int b, p, NT;
    if (tid < nP0) { T = gt; b = tid / halfN; p = tid - b * halfN; NT = N; }
    else { int u = tid - nP0; T = pp; b = u / halfM; p = u - b * halfM; NT = M; }
    const float* tb = T + ((size_t)b * NT + 2 * (size_t)p) * 3;
    float xA = tb[0], yA = tb[1], zA = tb[2];
    float xB = tb[3], yB = tb[4], zB = tb[5];
    HP[2 * (size_t)tid]     = make_float4(-2.f * zA, -2.f * zB, -2.f * yA, -2.f * yB);
    HP[2 * (size_t)tid + 1] = make_float4(-2.f * xA, -2.f * xB,
                                          xA * xA + yA * yA + zA * zA,
                                          xB * xB + yB * yB + zB * zB);
}

// dir 0: queries = pred (pc_p), targets = gt  -> P region
// dir 1: queries = gt  (pc_gt), targets = pred -> G region
// Hybrid operand streaming: LP pairs from LDS (staggered reads, ds pipe),
// PAIRS-LP pairs via wave-uniform global loads (SMEM/L1 pipe) — splits the
// operand stream across two pipes since LDS instr service (~24.5 cyc/wave-op,
// r5-r8 invariant) is the measured bottleneck.
template <bool USE_ATOMIC>
__global__ __launch_bounds__(BLK) void chamfer_min(
    const float* __restrict__ gt, const float* __restrict__ pp,
    const float4* __restrict__ HP,
    unsigned int* __restrict__ minP, unsigned int* __restrict__ minG,
    float* __restrict__ dP, float* __restrict__ dG,
    int M, int N)
{
    const int dir = (blockIdx.z >= SLICES) ? 1 : 0;
    const int s   = blockIdx.z - dir * SLICES;
    const float* __restrict__ Q = dir ? gt : pp;
    const int NQ = dir ? N : M;
    const int NT = dir ? M : N;
    const int b  = blockIdx.y;

    // uniform base of this slice's pair data (dir-major, then batch, then pair)
    const size_t dirbase = dir ? (size_t)8 * (N >> 1) : 0;
    const float4* __restrict__ gH =
        HP + 2 * (dirbase + (size_t)b * (NT >> 1) + (size_t)s * PAIRS);

    // LDS quarter: pairs [0, LP), duplicated to 2*LP entries for staggered reads
    __shared__ float4 sH0[2 * LP];
    __shared__ float4 sH1[2 * LP];
    {
        const int t = threadIdx.x;
        if (t < 2 * LP) {
            int j = t & (LP - 1);
            sH0[t] = gH[2 * j];
            sH1[t] = gH[2 * j + 1];
        }
    }
    __syncthreads();

    const int q0 = blockIdx.x * (BLK * QPT) + threadIdx.x * QPT;
    if (q0 >= NQ) return;

    // 8 query points = 24 floats = 6 aligned float4 loads -> named scalars
    const float4* qv = (const float4*)(Q + ((size_t)b * NQ + q0) * 3);
    float4 f0 = qv[0], f1 = qv[1], f2 = qv[2], f3 = qv[3], f4 = qv[4], f5 = qv[5];

#define DECLQ(i) float qx##i, qy##i, qz##i, bb##i = 3.0e38f;
    Q_ITER(DECLQ)
#undef DECLQ
    qx0 = f0.x; qy0 = f0.y; qz0 = f0.z;
    qx1 = f0.w; qy1 = f1.x; qz1 = f1.y;
    qx2 = f1.z; qy2 = f1.w; qz2 = f2.x;
    qx3 = f2.y; qy3 = f2.z; qz3 = f2.w;
    qx4 = f3.x; qy4 = f3.y; qz4 = f3.z;
    qx5 = f3.w; qy5 = f4.x; qz5 = f4.y;
    qx6 = f4.z; qy6 = f4.w; qz6 = f5.x;
    qx7 = f5.y; qy7 = f5.z; qz7 = f5.w;

#define DUPQ(i) f32x2 px##i = {qx##i, qx##i}, py##i = {qy##i, qy##i}, pz##i = {qz##i, qz##i};
    Q_ITER(DUPQ)
#undef DUPQ

#define STEP(i) { \
        f32x2 AB = __builtin_elementwise_fma(pz##i, Sz, Sw); \
        AB = __builtin_elementwise_fma(py##i, Sy, AB); \
        AB = __builtin_elementwise_fma(px##i, Sx, AB); \
        bb##i = fminf(fminf(bb##i, AB.x), AB.y); }
#define PROC(H0, H1) { \
        f32x2 Sz = {(H0).x, (H0).y}, Sy = {(H0).z, (H0).w}; \
        f32x2 Sx = {(H1).x, (H1).y}, Sw = {(H1).z, (H1).w}; \
        Q_ITER(STEP) }

    const int lane = threadIdx.x & 63;
    for (int i = 0; i < LP; ++i) {
        // 1 pair from LDS (staggered: lane reads pair (i+lane)&(LP-1))
        float4 a0 = sH0[i + lane];
        float4 a1 = sH1[i + lane];
        PROC(a0, a1)
        // 3 pairs via wave-uniform global loads (SMEM/L1 pipe, not LDS)
        const int g = LP + 3 * i;
        float4 b0 = gH[2 * g],     b1 = gH[2 * g + 1];
        PROC(b0, b1)
        float4 c0 = gH[2 * g + 2], c1 = gH[2 * g + 3];
        PROC(c0, c1)
        float4 d0 = gH[2 * g + 4], d1 = gH[2 * g + 5];
        PROC(d0, d1)
    }
#undef PROC
#undef STEP

    unsigned int* mp = (dir ? minG : minP) + (size_t)b * NQ + q0;
    float* op = (dir ? dG : dP) + (size_t)s * ((size_t)gridDim.y * NQ)
                                + (size_t)b * NQ + q0;
#define FIN(i) { \
        float aq = __builtin_fmaf(qx##i, qx##i, \
                   __builtin_fmaf(qy##i, qy##i, qz##i * qz##i)); \
        float d = fmaxf(bb##i + aq, 0.f); \
        if (USE_ATOMIC) atomicMin(&mp[i], __float_as_uint(d)); \
        else op[i] = d; }
    Q_ITER(FIN)
#undef FIN
}

__device__ double block_reduce_d(double v) {
    __shared__ double red[4];
    for (int o = 32; o > 0; o >>= 1) v += __shfl_down(v, o);
    int lane = threadIdx.x & 63, w = threadIdx.x >> 6;
    if (lane == 0) red[w] = v;
    __syncthreads();
    if (threadIdx.x == 0) v = red[0] + red[1] + red[2] + red[3];
    return v;
}

// fold SLICES per-slice mins + weighted sum
__global__ __launch_bounds__(256) void reduce1_slices(
    const float* __restrict__ dP, const float* __restrict__ dG,
    double* __restrict__ partials, int EM, int EN, double wP, double wG) {
    const int E = EM + EN;
    double acc = 0.0;
    for (int i = blockIdx.x * 256 + threadIdx.x; i < E; i += 256 * 256) {
        const float* base; int stride; double w;
        if (i < EM) { base = dP + i;        stride = EM; w = wP; }
        else        { base = dG + (i - EM); stride = EN; w = wG; }
        float m = base[0];
#pragma unroll
        for (int s = 1; s < SLICES; ++s) m = fminf(m, base[(size_t)s * stride]);
        acc += (double)m * w;
    }
    double s = block_reduce_d(acc);
    if (threadIdx.x == 0) partials[blockIdx.x] = s;
}

__global__ __launch_bounds__(256) void reduce1_atomic(
    const unsigned int* __restrict__ mins, double* __restrict__ partials,
    int EM, int E, double wP, double wG) {
    double acc = 0.0;
    for (int i = blockIdx.x * 256 + threadIdx.x; i < E; i += 256 * 256)
        acc += (double)__uint_as_float(mins[i]) * (i < EM ? wP : wG);
    double s = block_reduce_d(acc);
    if (threadIdx.x == 0) partials[blockIdx.x] = s;
}

__global__ __launch_bounds__(256) void reduce2(const double* __restrict__ partials,
                                               float* __restrict__ out) {
    double s = block_reduce_d(partials[threadIdx.x]);
    if (threadIdx.x == 0) out[0] = (float)s;
}

extern "C" void kernel_launch(void* const* d_in, const int* in_sizes, int n_in,
                              void* d_out, int out_size, void* d_ws, size_t ws_size,
                              hipStream_t stream) {
    const float* gt = (const float*)d_in[0];  // pc_gt (B,N,3)
    const float* pp = (const float*)d_in[1];  // pc_p  (B,M,3)
    const int B = 8;
    const int N = in_sizes[0] / (B * 3);
    const int M = in_sizes[1] / (B * 3);
    const int EM = B * M, EN = B * N, E = EM + EN;
    float* out = (float*)d_out;

    const int TP = B * (N >> 1) + B * (M >> 1);   // total pairs (both dirs)
    const size_t hpBytes = (size_t)TP * 32;       // 2 float4 per pair

    char* w = (char*)d_ws;
    float4* HP = (float4*)w;

    prep_pairs<<<(TP + 255) / 256, 256, 0, stream>>>(gt, pp, HP, M, N);

    const int NQmax = (M > N) ? M : N;
    dim3 grid((NQmax + BLK * QPT - 1) / (BLK * QPT), B, 2 * SLICES);

    const size_t needMain = hpBytes + (size_t)SLICES * E * 4 + 256 * 8;
    if (ws_size >= needMain) {
        float* dP = (float*)(w + hpBytes);              // SLICES x EM
        float* dG = dP + (size_t)SLICES * EM;           // SLICES x EN
        double* partials = (double*)(w + hpBytes + (size_t)SLICES * E * 4);
        chamfer_min<false><<<grid, BLK, 0, stream>>>(gt, pp, HP, nullptr, nullptr,
                                                     dP, dG, M, N);
        reduce1_slices<<<256, 256, 0, stream>>>(dP, dG, partials, EM, EN,
                                                1.0 / (double)EM, 1.0 / (double)EN);
        reduce2<<<1, 256, 0, stream>>>(partials, out);
    } else {
        // fallback: atomic-min path
        unsigned int* mins = (unsigned int*)(w + hpBytes);
        double* partials = (double*)(w + hpBytes + (size_t)E * 4);
        init_mins<<<(E + 255) / 256, 256, 0, stream>>>(mins, E);
        chamfer_min<true><<<grid, BLK, 0, stream>>>(gt, pp, HP, mins, mins + EM,
                                                    nullptr, nullptr, M, N);
        reduce1_atomic<<<256, 256, 0, stream>>>(mins, partials, EM, E,
                                                1.0 / (double)EM, 1.0 / (double)EN);
        reduce2<<<1, 256, 0, stream>>>(partials, out);
    }
}

// Round 12
// 89.119 us; speedup vs baseline: 1.1535x; 1.1429x over previous
//
#include <hip/hip_runtime.h>

#define BLK 256
#define QPT 8        // query points per thread (named scalars, fits <64 VGPR)
#define SLICES 32    // target slices per direction
#define TT 256       // targets per slice tile (= 8192 / SLICES)

#define Q_ITER(F) F(0) F(1) F(2) F(3) F(4) F(5) F(6) F(7)

__global__ __launch_bounds__(256) void init_mins(unsigned int* mins, int n) {
    int i = blockIdx.x * 256 + threadIdx.x;
    if (i < n) mins[i] = 0x7f800000u;  // +inf
}

// dir 0: queries = pred (pc_p), targets = gt  -> P region
// dir 1: queries = gt  (pc_gt), targets = pred -> G region
// r5 structure + 2-iteration-deep register prefetch: reads for pair j+4 are
// issued before processing pair j (read->use distance ~224 cyc > 120-cyc LDS
// latency, m117), to break the latency chain that r5-r8 counters show is the
// limiter (VALU<=57%, LDS<=48% busy -> neither pipe saturated).
template <bool USE_ATOMIC>
__global__ __launch_bounds__(BLK) void chamfer_min(
    const float* __restrict__ gt, const float* __restrict__ pp,
    unsigned int* __restrict__ minP, unsigned int* __restrict__ minG,
    float* __restrict__ dP, float* __restrict__ dG,
    int M, int N)
{
    const int dir = (blockIdx.z >= SLICES) ? 1 : 0;
    const int s   = blockIdx.z - dir * SLICES;
    const float* __restrict__ Q = dir ? gt : pp;
    const float* __restrict__ T = dir ? pp : gt;
    const int NQ = dir ? N : M;
    const int NT = dir ? M : N;
    const int b  = blockIdx.y;

    // stage target slice into LDS as (-2x, -2y, -2z, |t|^2)
    __shared__ float4 sT[TT];
    {
        const float* tb = T + ((size_t)b * NT + (size_t)s * TT) * 3;
        for (int j = threadIdx.x; j < TT; j += BLK) {
            float x = tb[3 * j], y = tb[3 * j + 1], z = tb[3 * j + 2];
            sT[j] = make_float4(-2.f * x, -2.f * y, -2.f * z,
                                x * x + y * y + z * z);
        }
    }
    __syncthreads();

    const int q0 = blockIdx.x * (BLK * QPT) + threadIdx.x * QPT;
    if (q0 >= NQ) return;

    // 8 query points = 24 floats = 6 aligned float4 loads -> named scalars
    const float4* qv = (const float4*)(Q + ((size_t)b * NQ + q0) * 3);
    float4 f0 = qv[0], f1 = qv[1], f2 = qv[2], f3 = qv[3], f4 = qv[4], f5 = qv[5];

#define DECLQ(i) float qx##i, qy##i, qz##i, bb##i = 3.0e38f;
    Q_ITER(DECLQ)
#undef DECLQ
    qx0 = f0.x; qy0 = f0.y; qz0 = f0.z;
    qx1 = f0.w; qy1 = f1.x; qz1 = f1.y;
    qx2 = f1.z; qy2 = f1.w; qz2 = f2.x;
    qx3 = f2.y; qy3 = f2.z; qz3 = f2.w;
    qx4 = f3.x; qy4 = f3.y; qz4 = f3.z;
    qx5 = f3.w; qy5 = f4.x; qz5 = f4.y;
    qx6 = f4.z; qy6 = f4.w; qz6 = f5.x;
    qx7 = f5.y; qy7 = f5.z; qz7 = f5.w;

    // min over targets of (|t|^2 - 2 q.t); add |q|^2 back at the end.
    // Column pairs: fminf(fminf(bb,A),B) -> v_min3_f32.
    // Software pipeline: cur (c0,c1), next (n0,n1), prefetch (p0,p1).
    float4 c0 = sT[0], c1 = sT[1];
    float4 n0 = sT[2], n1 = sT[3];
#pragma unroll 2
    for (int j = 0; j < TT; j += 2) {
        const int ja = (j + 4) & (TT - 1);   // wrapped prefetch (tail data unused)
        float4 p0 = sT[ja];
        float4 p1 = sT[ja + 1];
#define STEP(i) { \
        float A  = __builtin_fmaf(qz##i, c0.z, c0.w); \
        float Bv = __builtin_fmaf(qz##i, c1.z, c1.w); \
        A  = __builtin_fmaf(qy##i, c0.y, A); \
        Bv = __builtin_fmaf(qy##i, c1.y, Bv); \
        A  = __builtin_fmaf(qx##i, c0.x, A); \
        Bv = __builtin_fmaf(qx##i, c1.x, Bv); \
        bb##i = fminf(fminf(bb##i, A), Bv); }
        Q_ITER(STEP)
#undef STEP
        c0 = n0; c1 = n1; n0 = p0; n1 = p1;
    }

    unsigned int* mp = (dir ? minG : minP) + (size_t)b * NQ + q0;
    float* op = (dir ? dG : dP) + (size_t)s * ((size_t)gridDim.y * NQ)
                                + (size_t)b * NQ + q0;
#define FIN(i) { \
        float aq = __builtin_fmaf(qx##i, qx##i, \
                   __builtin_fmaf(qy##i, qy##i, qz##i * qz##i)); \
        float d = fmaxf(bb##i + aq, 0.f); \
        if (USE_ATOMIC) atomicMin(&mp[i], __float_as_uint(d)); \
        else op[i] = d; }
    Q_ITER(FIN)
#undef FIN
}

__device__ double block_reduce_d(double v) {
    __shared__ double red[4];
    for (int o = 32; o > 0; o >>= 1) v += __shfl_down(v, o);
    int lane = threadIdx.x & 63, w = threadIdx.x >> 6;
    if (lane == 0) red[w] = v;
    __syncthreads();
    if (threadIdx.x == 0) v = red[0] + red[1] + red[2] + red[3];
    return v;
}

// fold SLICES per-slice mins + weighted sum
__global__ __launch_bounds__(256) void reduce1_slices(
    const float* __restrict__ dP, const float* __restrict__ dG,
    double* __restrict__ partials, int EM, int EN, double wP, double wG) {
    const int E = EM + EN;
    double acc = 0.0;
    for (int i = blockIdx.x * 256 + threadIdx.x; i < E; i += 256 * 256) {
        const float* base; int stride; double w;
        if (i < EM) { base = dP + i;        stride = EM; w = wP; }
        else        { base = dG + (i - EM); stride = EN; w = wG; }
        float m = base[0];
#pragma unroll
        for (int s = 1; s < SLICES; ++s) m = fminf(m, base[(size_t)s * stride]);
        acc += (double)m * w;
    }
    double s = block_reduce_d(acc);
    if (threadIdx.x == 0) partials[blockIdx.x] = s;
}

__global__ __launch_bounds__(256) void reduce1_atomic(
    const unsigned int* __restrict__ mins, double* __restrict__ partials,
    int EM, int E, double wP, double wG) {
    double acc = 0.0;
    for (int i = blockIdx.x * 256 + threadIdx.x; i < E; i += 256 * 256)
        acc += (double)__uint_as_float(mins[i]) * (i < EM ? wP : wG);
    double s = block_reduce_d(acc);
    if (threadIdx.x == 0) partials[blockIdx.x] = s;
}

__global__ __launch_bounds__(256) void reduce2(const double* __restrict__ partials,
                                               float* __restrict__ out) {
    double s = block_reduce_d(partials[threadIdx.x]);
    if (threadIdx.x == 0) out[0] = (float)s;
}

extern "C" void kernel_launch(void* const* d_in, const int* in_sizes, int n_in,
                              void* d_out, int out_size, void* d_ws, size_t ws_size,
                              hipStream_t stream) {
    const float* gt = (const float*)d_in[0];  // pc_gt (B,N,3)
    const float* pp = (const float*)d_in[1];  // pc_p  (B,M,3)
    const int B = 8;
    const int N = in_sizes[0] / (B * 3);
    const int M = in_sizes[1] / (B * 3);
    const int EM = B * M, EN = B * N, E = EM + EN;
    float* out = (float*)d_out;

    const int NQmax = (M > N) ? M : N;
    dim3 grid((NQmax + BLK * QPT - 1) / (BLK * QPT), B, 2 * SLICES);

    const size_t needNA = (size_t)SLICES * E * 4 + 256 * 8;
    if (ws_size >= needNA) {
        // no-atomic path: per-slice buffers + fused slice-min reduction
        float* dP = (float*)d_ws;                       // SLICES x EM
        float* dG = dP + (size_t)SLICES * EM;           // SLICES x EN
        double* partials = (double*)((char*)d_ws + (size_t)SLICES * E * 4);
        chamfer_min<false><<<grid, BLK, 0, stream>>>(gt, pp, nullptr, nullptr,
                                                     dP, dG, M, N);
        reduce1_slices<<<256, 256, 0, stream>>>(dP, dG, partials, EM, EN,
                                                1.0 / (double)EM, 1.0 / (double)EN);
        reduce2<<<1, 256, 0, stream>>>(partials, out);
    } else {
        // fallback: atomic-min path
        unsigned int* mins = (unsigned int*)d_ws;
        double* partials = (double*)((char*)d_ws + (size_t)E * 4);
        init_mins<<<(E + 255) / 256, 256, 0, stream>>>(mins, E);
        chamfer_min<true><<<grid, BLK, 0, stream>>>(gt, pp, mins, mins + EM,
                                                    nullptr, nullptr, M, N);
        reduce1_atomic<<<256, 256, 0, stream>>>(mins, partials, EM, E,
                                                1.0 / (double)EM, 1.0 / (double)EN);
        reduce2<<<1, 256, 0, stream>>>(partials, out);
    }
}

// Round 13
// 69.862 us; speedup vs baseline: 1.4714x; 1.2756x over previous
//
#include <hip/hip_runtime.h>

typedef float f32x16 __attribute__((ext_vector_type(16)));
typedef short short8 __attribute__((ext_vector_type(8)));

// ---- bf16 helpers (RNE) ----
__device__ __forceinline__ unsigned short b16(float f) {
    unsigned int u = __float_as_uint(f);
    return (unsigned short)((u + 0x7fffu + ((u >> 16) & 1u)) >> 16);
}
__device__ __forceinline__ float fb16(unsigned short s) {
    return __uint_as_float(((unsigned int)s) << 16);
}

// Precompute per-target B-fragments for mfma_f32_32x32x16_bf16.
// For target t: m = -2t. Split m and w=|t|^2 into bf16 hi/lo (w 3-way).
// K-slot layout (paired with A): k0..2 qh*mh, k3..5 qh*ml, k6..8 ql*mh,
// k9..11 1.0*(wh,wm,wl), k12..15 zero.
// B lane layout: col = lane&31, k = 8*(lane>>5)+j  ->  fragment per lane = 16B.
// BT[tile][lane] contiguous so LDS staging/read is lane-linear.
__global__ __launch_bounds__(256) void prep_bt(
    const float* __restrict__ gt, const float* __restrict__ pp,
    short8* __restrict__ BT, int M, int N)
{
    int t = blockIdx.x * 256 + threadIdx.x;
    const int n0 = 8 * N;
    if (t >= n0 + 8 * M) return;
    int dir = t >= n0 ? 1 : 0;
    int local = dir ? t - n0 : t;
    int NT = dir ? M : N;
    const float* T = dir ? pp : gt;
    int b = local / NT, tt = local - b * NT;
    const float* c = T + ((size_t)b * NT + tt) * 3;
    float x = c[0], y = c[1], z = c[2];
    float mx = -2.f * x, my = -2.f * y, mz = -2.f * z;
    unsigned short mhx = b16(mx), mhy = b16(my), mhz = b16(mz);
    unsigned short mlx = b16(mx - fb16(mhx));
    unsigned short mly = b16(my - fb16(mhy));
    unsigned short mlz = b16(mz - fb16(mhz));
    float w = __builtin_fmaf(x, x, __builtin_fmaf(y, y, z * z));
    unsigned short wh = b16(w);
    float r1 = w - fb16(wh);
    unsigned short wm = b16(r1);
    unsigned short wl = b16(r1 - fb16(wm));
    int tile = tt >> 5, col = tt & 31;
    size_t tbase = (dir ? (size_t)8 * (N >> 5) + (size_t)b * (M >> 5)
                        : (size_t)b * (N >> 5)) + tile;
    short8 lo, hi;
    lo[0] = (short)mhx; lo[1] = (short)mhy; lo[2] = (short)mhz;
    lo[3] = (short)mlx; lo[4] = (short)mly; lo[5] = (short)mlz;
    lo[6] = (short)mhx; lo[7] = (short)mhy;
    hi[0] = (short)mhz; hi[1] = (short)wh; hi[2] = (short)wm; hi[3] = (short)wl;
    hi[4] = 0; hi[5] = 0; hi[6] = 0; hi[7] = 0;
    BT[tbase * 64 + col]      = lo;
    BT[tbase * 64 + 32 + col] = hi;
}

// One wave = 32 queries vs ALL targets of its (dir,b): min completes in-wave.
// Per tile (32 targets): 1 ds_read_b128 (B frag) + 1 MFMA + 16 v_min.
// dir 0: queries = pred(pp), targets = gt -> dP.  dir 1: queries = gt -> dG.
__global__ __launch_bounds__(256) void chamfer_mfma(
    const float* __restrict__ gt, const float* __restrict__ pp,
    const short8* __restrict__ BT,
    float* __restrict__ dP, float* __restrict__ dG,
    int M, int N)
{
    __shared__ short8 sB[2048];          // 32 tiles x 64 frags = 32 KB
    const int nb0 = 8 * (M >> 7);
    int bid = blockIdx.x;
    int dir = bid >= nb0 ? 1 : 0;
    int lb  = dir ? bid - nb0 : bid;
    int NQ  = dir ? N : M;
    int NT  = dir ? M : N;
    int qchunks = NQ >> 7;
    int b  = lb / qchunks;
    int qc = lb - b * qchunks;
    const float* Q = dir ? gt : pp;
    float* outD = dir ? dG : dP;
    size_t tb_base = dir ? (size_t)8 * (N >> 5) + (size_t)b * (M >> 5)
                         : (size_t)b * (N >> 5);
    const short8* gB = BT + tb_base * 64;

    const int tid = threadIdx.x;
    const int wv = tid >> 6, l = tid & 63;
    const int lane = l & 31, hi = l >> 5;
    const int q0 = (qc << 7) + (wv << 5);

    // A fragment: row = lane&31 (query), k = 8*hi + j.
    // low lanes k0..7:  [qhx,qhy,qhz, qhx,qhy,qhz, qlx,qly]
    // high lanes k8..15:[qlz, 1, 1, 1, 0,0,0,0]
    const float* qp = Q + ((size_t)b * NQ + q0 + lane) * 3;
    float x = qp[0], y = qp[1], z = qp[2];
    unsigned short qhx = b16(x), qhy = b16(y), qhz = b16(z);
    unsigned short qlx = b16(x - fb16(qhx));
    unsigned short qly = b16(y - fb16(qhy));
    unsigned short qlz = b16(z - fb16(qhz));
    const unsigned short ONE = 0x3F80;
    short8 af;
    af[0] = (short)(hi ? qlz : qhx);
    af[1] = (short)(hi ? ONE : qhy);
    af[2] = (short)(hi ? ONE : qhz);
    af[3] = (short)(hi ? ONE : qhx);
    af[4] = (short)(hi ? 0   : qhy);
    af[5] = (short)(hi ? 0   : qhz);
    af[6] = (short)(hi ? 0   : qlx);
    af[7] = (short)(hi ? 0   : qly);

    f32x16 cz;
#pragma unroll
    for (int k = 0; k < 16; ++k) cz[k] = 0.f;
    f32x16 bb;
#pragma unroll
    for (int k = 0; k < 16; ++k) bb[k] = 3.0e38f;

    const int chunks = NT >> 10;         // tiles(NT/32) / 32 per chunk
    for (int c = 0; c < chunks; ++c) {
        __syncthreads();                 // protect previous chunk's reads
#pragma unroll
        for (int jj = 0; jj < 8; ++jj)
            sB[jj * 256 + tid] = gB[(size_t)c * 2048 + jj * 256 + tid];
        __syncthreads();
#pragma unroll 4
        for (int j = 0; j < 32; ++j) {
            short8 bf = sB[j * 64 + l];
            f32x16 d = __builtin_amdgcn_mfma_f32_32x32x16_bf16(af, bf, cz, 0, 0, 0);
            bb = __builtin_elementwise_min(bb, d);   // d = |t|^2 - 2 q.t
        }
    }

    // cross-lane min over 32 target-columns (within each half-wave), then one
    // lane per (row,half) stores. C/D: col=lane&31, row=(r&3)+8*(r>>2)+4*hi.
    float* ob = outD + (size_t)b * NQ + q0;
#pragma unroll
    for (int r = 0; r < 16; ++r) {
        float v = bb[r];
        v = fminf(v, __shfl_xor(v, 1));
        v = fminf(v, __shfl_xor(v, 2));
        v = fminf(v, __shfl_xor(v, 4));
        v = fminf(v, __shfl_xor(v, 8));
        v = fminf(v, __shfl_xor(v, 16));
        int qrow = (r & 3) + 8 * (r >> 2) + 4 * hi;
        if (lane == qrow) ob[qrow] = v;
    }
}

__device__ double block_reduce_d(double v) {
    __shared__ double red[4];
    for (int o = 32; o > 0; o >>= 1) v += __shfl_down(v, o);
    int lane = threadIdx.x & 63, w = threadIdx.x >> 6;
    if (lane == 0) red[w] = v;
    __syncthreads();
    if (threadIdx.x == 0) v = red[0] + red[1] + red[2] + red[3];
    return v;
}

// add |q|^2, clamp, weighted mean
__global__ __launch_bounds__(256) void reduce_fin(
    const float* __restrict__ gt, const float* __restrict__ pp,
    const float* __restrict__ dP, const float* __restrict__ dG,
    double* __restrict__ partials, int EM, int EN, double wP, double wG)
{
    const int E = EM + EN;
    double acc = 0.0;
    for (int i = blockIdx.x * 256 + threadIdx.x; i < E; i += 256 * 256) {
        const float* c; float dm; double w;
        if (i < EM) { c = pp + (size_t)3 * i;        dm = dP[i];      w = wP; }
        else        { c = gt + (size_t)3 * (i - EM); dm = dG[i - EM]; w = wG; }
        float x = c[0], y = c[1], z = c[2];
        float d = fmaxf(dm + __builtin_fmaf(x, x, __builtin_fmaf(y, y, z * z)), 0.f);
        acc += (double)d * w;
    }
    double s = block_reduce_d(acc);
    if (threadIdx.x == 0) partials[blockIdx.x] = s;
}

__global__ __launch_bounds__(256) void reduce2(const double* __restrict__ partials,
                                               float* __restrict__ out) {
    double s = block_reduce_d(partials[threadIdx.x]);
    if (threadIdx.x == 0) out[0] = (float)s;
}

extern "C" void kernel_launch(void* const* d_in, const int* in_sizes, int n_in,
                              void* d_out, int out_size, void* d_ws, size_t ws_size,
                              hipStream_t stream) {
    const float* gt = (const float*)d_in[0];  // pc_gt (B,N,3)
    const float* pp = (const float*)d_in[1];  // pc_p  (B,M,3)
    const int B = 8;
    const int N = in_sizes[0] / (B * 3);
    const int M = in_sizes[1] / (B * 3);
    const int EM = B * M, EN = B * N;
    float* out = (float*)d_out;

    short8* BT = (short8*)d_ws;
    size_t ntiles = (size_t)8 * (N >> 5) + (size_t)8 * (M >> 5);
    size_t btBytes = ntiles * 64 * sizeof(short8);          // 4 MB at 8192
    float* dP = (float*)((char*)d_ws + btBytes);            // EM floats
    float* dG = dP + (size_t)EM;                            // EN floats
    double* partials = (double*)(dG + (size_t)EN);          // 256 doubles

    int totT = 8 * (N + M);
    prep_bt<<<(totT + 255) / 256, 256, 0, stream>>>(gt, pp, BT, M, N);

    int nb = 8 * (M >> 7) + 8 * (N >> 7);
    chamfer_mfma<<<nb, 256, 0, stream>>>(gt, pp, BT, dP, dG, M, N);

    reduce_fin<<<256, 256, 0, stream>>>(gt, pp, dP, dG, partials, EM, EN,
                                        1.0 / (double)EM, 1.0 / (double)EN);
    reduce2<<<1, 256, 0, stream>>>(partials, out);
}